// Round 1
// baseline (1216.460 us; speedup 1.0000x reference)
//
#include <hip/hip_runtime.h>
#include <hip/hip_bf16.h>

// Problem constants (fixed by setup_inputs)
#define NTOT   102400          // TOTAL_NODES
#define NSEG   2048            // NUM_SEG
#define HID    128
#define VOCAB  100000
#define NCOLS  99999           // VOCAB-1 output columns

typedef __attribute__((ext_vector_type(8))) short bf16x8;  // 8 bf16 = 4 VGPR (guide §3)
typedef __attribute__((ext_vector_type(4))) float f32x4;   // 16x16 MFMA accumulator

// fp32 -> bf16 round-to-nearest-even
__device__ __forceinline__ short f2bf(float f) {
    union { float f; unsigned u; } v; v.f = f;
    unsigned r = v.u + 0x7FFFu + ((v.u >> 16) & 1u);
    return (short)(r >> 16);
}

__device__ __forceinline__ float sigmoidf_(float x) {
    return 1.0f / (1.0f + __expf(-x));
}

// ---------------------------------------------------------------------------
// 0) detect batch dtype: int32 layout iff last int32 element == NSEG-1
//    (sorted, every segment non-empty => true last value is 2047; if the
//     buffer is int64, int32 index NTOT-1 is a high word == 0)
__global__ void detect_kernel(const int* braw, int* flag) {
    if (threadIdx.x == 0) *flag = (braw[NTOT - 1] == NSEG - 1) ? 1 : 0;
}

// 1) normalize batch to int32 + find last index of each segment
__global__ void prep_kernel(const int* braw, const int* flag, int* batch_n, int* last_idx) {
    int i = blockIdx.x * blockDim.x + threadIdx.x;
    if (i >= NTOT) return;
    int is32 = *flag;
    int v, vn;
    if (is32) { v = braw[i];     vn = (i < NTOT - 1) ? braw[i + 1]     : -1; }
    else      { v = braw[2 * i]; vn = (i < NTOT - 1) ? braw[2 * i + 2] : -1; }
    batch_n[i] = v;
    if (i == NTOT - 1 || vn != v) last_idx[v] = i;
}

// 2) emb_weight[1:] -> bf16 (read 51.2MB, write 25.6MB, once)
__global__ void convE_kernel(const float* __restrict__ emb, short* __restrict__ Ebf) {
    const int n4 = NCOLS * HID / 4;   // 3,199,968 float4s
    int t = blockIdx.x * blockDim.x + threadIdx.x;
    if (t >= n4) return;
    float4 f = *(const float4*)(emb + HID + (size_t)t * 4);  // +HID skips row 0
    short4 s; s.x = f2bf(f.x); s.y = f2bf(f.y); s.z = f2bf(f.z); s.w = f2bf(f.w);
    *(short4*)(Ebf + (size_t)t * 4) = s;
}

// 3) w1_vn[b] = x[last_idx[b]] @ W1^T + W1_b   (tiny: 67 MFLOP)
__global__ __launch_bounds__(128) void w1_kernel(const float* __restrict__ x,
        const float* __restrict__ W1w, const float* __restrict__ W1b,
        const int* __restrict__ last_idx, float* __restrict__ w1_vn) {
    int b = blockIdx.x, t = threadIdx.x;
    __shared__ __align__(16) float v[HID];
    int li = last_idx[b];
    v[t] = x[(size_t)li * HID + t];
    __syncthreads();
    const float4* wr = (const float4*)(W1w + t * HID);
    const float4* vv = (const float4*)v;
    float acc = W1b[t];
    #pragma unroll
    for (int k = 0; k < HID / 4; ++k) {
        float4 w = wr[k]; float4 a = vv[k];
        acc += w.x * a.x + w.y * a.y + w.z * a.z + w.w * a.w;
    }
    w1_vn[b * HID + t] = acc;
}

// 4) h = sigmoid(w1_vn[batch] + x@W2^T + b2); alpha = h@q^T + q_b
//    MFMA bf16 GEMM (on-the-fly fp32->bf16), fused alpha epilogue.
//    Wave handles 16 node-rows x all 128 cols (8 n-frags, 4 k-steps).
__global__ __launch_bounds__(256) void halpha_kernel(const float* __restrict__ x,
        const float* __restrict__ W2w, const float* __restrict__ W2b,
        const float* __restrict__ qw, const float* __restrict__ qb,
        const float* __restrict__ w1_vn, const int* __restrict__ batch_n,
        float* __restrict__ alpha) {
    int tid = threadIdx.x;
    int wave = tid >> 6, lane = tid & 63, quad = lane >> 4, l15 = lane & 15;
    int m0 = blockIdx.x * 64 + wave * 16;

    const f32x4 fz = {0.f, 0.f, 0.f, 0.f};
    f32x4 acc[8];
    #pragma unroll
    for (int t = 0; t < 8; ++t) acc[t] = fz;

    #pragma unroll
    for (int ks = 0; ks < 4; ++ks) {
        int kb = ks * 32 + quad * 8;
        // A frag: x[m0+l15][kb..kb+7]  (A[m=lane&15][k=quad*8+j] layout)
        const float* ap = x + (size_t)(m0 + l15) * HID + kb;
        float4 lo = *(const float4*)ap, hi = *(const float4*)(ap + 4);
        bf16x8 a;
        a[0] = f2bf(lo.x); a[1] = f2bf(lo.y); a[2] = f2bf(lo.z); a[3] = f2bf(lo.w);
        a[4] = f2bf(hi.x); a[5] = f2bf(hi.y); a[6] = f2bf(hi.z); a[7] = f2bf(hi.w);
        #pragma unroll
        for (int t = 0; t < 8; ++t) {
            const float* bp = W2w + (size_t)(t * 16 + l15) * HID + kb;
            float4 blo = *(const float4*)bp, bhi = *(const float4*)(bp + 4);
            bf16x8 bb;
            bb[0] = f2bf(blo.x); bb[1] = f2bf(blo.y); bb[2] = f2bf(blo.z); bb[3] = f2bf(blo.w);
            bb[4] = f2bf(bhi.x); bb[5] = f2bf(bhi.y); bb[6] = f2bf(bhi.z); bb[7] = f2bf(bhi.w);
            acc[t] = __builtin_amdgcn_mfma_f32_16x16x32_bf16(a, bb, acc[t], 0, 0, 0);
        }
    }
    // epilogue: C/D layout col=lane&15, row=quad*4+reg (guide §3, m89-verified)
    float qbv = qb[0];
    #pragma unroll
    for (int r = 0; r < 4; ++r) {
        int m = m0 + quad * 4 + r;
        const float* w1row = w1_vn + (size_t)batch_n[m] * HID;
        float s = 0.f;
        #pragma unroll
        for (int t = 0; t < 8; ++t) {
            int c = t * 16 + l15;
            float pre = acc[t][r] + W2b[c] + w1row[c];
            s += sigmoidf_(pre) * qw[c];
        }
        // reduce over the 16 lanes of the quad (cols)
        s += __shfl_xor(s, 1); s += __shfl_xor(s, 2);
        s += __shfl_xor(s, 4); s += __shfl_xor(s, 8);
        if (l15 == r) alpha[m] = s + qbv;
    }
}

// 5) s_g[b] = sum_{i in seg b} alpha[i] * x[i]   (segments are contiguous)
__global__ __launch_bounds__(128) void sg_kernel(const float* __restrict__ x,
        const float* __restrict__ alpha, const int* __restrict__ last_idx,
        float* __restrict__ s_g) {
    int b = blockIdx.x, t = threadIdx.x;
    int start = (b == 0) ? 0 : last_idx[b - 1] + 1;
    int end = last_idx[b];
    float acc = 0.f;
    for (int i = start; i <= end; ++i)
        acc += alpha[i] * x[(size_t)i * HID + t];
    s_g[b * HID + t] = acc;
}

// 6) s_h[b] = concat(v_n[b], s_g[b]) @ W3^T + W3_b  -> bf16
__global__ __launch_bounds__(128) void sh_kernel(const float* __restrict__ x,
        const float* __restrict__ s_g, const float* __restrict__ W3w,
        const float* __restrict__ W3b, const int* __restrict__ last_idx,
        short* __restrict__ sh_bf) {
    int b = blockIdx.x, t = threadIdx.x;
    __shared__ __align__(16) float cat[2 * HID];
    int li = last_idx[b];
    cat[t] = x[(size_t)li * HID + t];
    cat[HID + t] = s_g[b * HID + t];
    __syncthreads();
    const float4* wr = (const float4*)(W3w + (size_t)t * 2 * HID);
    const float4* cc = (const float4*)cat;
    float acc = W3b[t];
    #pragma unroll
    for (int k = 0; k < 2 * HID / 4; ++k) {
        float4 w = wr[k]; float4 a = cc[k];
        acc += w.x * a.x + w.y * a.y + w.z * a.z + w.w * a.w;
    }
    sh_bf[b * HID + t] = f2bf(acc);
}

// 7) z[b][v] = s_h[b] . E_bf16[v]   [2048 x 99999], write-bound (~819MB)
//    Block = 128x128 tile, 4 waves in 2x2, wave = 64x64 (4x4 16x16 frags).
//    No LDS: A (s_h, 512KB) is L2-resident; B (E_bf16) served by L2/L3.
//    Grid x = m-blocks (16) so consecutive blocks share the same E tile.
__global__ __launch_bounds__(256) void final_kernel(const short* __restrict__ shb,
        const short* __restrict__ Ebf, float* __restrict__ out) {
    int tid = threadIdx.x;
    int wave = tid >> 6, lane = tid & 63, quad = lane >> 4, l15 = lane & 15;
    int m0 = blockIdx.x * 128 + (wave >> 1) * 64;
    int n0 = blockIdx.y * 128 + (wave & 1) * 64;

    const f32x4 fz = {0.f, 0.f, 0.f, 0.f};
    const bf16x8 zb = {0, 0, 0, 0, 0, 0, 0, 0};
    f32x4 acc[4][4];
    #pragma unroll
    for (int mt = 0; mt < 4; ++mt)
        #pragma unroll
        for (int nt = 0; nt < 4; ++nt) acc[mt][nt] = fz;

    #pragma unroll
    for (int ks = 0; ks < 4; ++ks) {
        int kb = ks * 32 + quad * 8;
        bf16x8 a[4], b[4];
        #pragma unroll
        for (int mt = 0; mt < 4; ++mt)
            a[mt] = *(const bf16x8*)(shb + (size_t)(m0 + mt * 16 + l15) * HID + kb);
        #pragma unroll
        for (int nt = 0; nt < 4; ++nt) {
            int vrow = n0 + nt * 16 + l15;
            b[nt] = (vrow < NCOLS) ? *(const bf16x8*)(Ebf + (size_t)vrow * HID + kb) : zb;
        }
        #pragma unroll
        for (int mt = 0; mt < 4; ++mt)
            #pragma unroll
            for (int nt = 0; nt < 4; ++nt)
                acc[mt][nt] = __builtin_amdgcn_mfma_f32_16x16x32_bf16(a[mt], b[nt], acc[mt][nt], 0, 0, 0);
    }

    #pragma unroll
    for (int mt = 0; mt < 4; ++mt) {
        #pragma unroll
        for (int r = 0; r < 4; ++r) {
            int m = m0 + mt * 16 + quad * 4 + r;
            float* orow = out + (size_t)m * NCOLS;
            #pragma unroll
            for (int nt = 0; nt < 4; ++nt) {
                int v = n0 + nt * 16 + l15;
                if (v < NCOLS) orow[v] = acc[mt][nt][r];
            }
        }
    }
}

// ---------------------------------------------------------------------------
extern "C" void kernel_launch(void* const* d_in, const int* in_sizes, int n_in,
                              void* d_out, int out_size, void* d_ws, size_t ws_size,
                              hipStream_t stream) {
    const float* x    = (const float*)d_in[0];
    const float* emb  = (const float*)d_in[1];
    const float* W1w  = (const float*)d_in[2];
    const float* W1b  = (const float*)d_in[3];
    const float* W2w  = (const float*)d_in[4];
    const float* W2b  = (const float*)d_in[5];
    const float* qw   = (const float*)d_in[6];
    const float* qb   = (const float*)d_in[7];
    const float* W3w  = (const float*)d_in[8];
    const float* W3b  = (const float*)d_in[9];
    const int*   braw = (const int*)d_in[10];
    float* out = (float*)d_out;

    // workspace layout (all offsets 256B-aligned), total ~27.7 MB
    char* ws = (char*)d_ws;
    int*   flag     = (int*)(ws + 0);
    int*   last_idx = (int*)(ws + 256);         // 2048 * 4
    int*   batch_n  = (int*)(ws + 8448);        // 102400 * 4
    float* w1_vn    = (float*)(ws + 418048);    // 2048*128 * 4
    float* alpha    = (float*)(ws + 1466624);   // 102400 * 4
    float* s_g      = (float*)(ws + 1876224);   // 2048*128 * 4
    short* sh_bf    = (short*)(ws + 2924800);   // 2048*128 * 2
    short* Ebf      = (short*)(ws + 3449088);   // 99999*128 * 2 -> ends 29,048,832

    detect_kernel<<<1, 64, 0, stream>>>(braw, flag);
    prep_kernel<<<400, 256, 0, stream>>>(braw, flag, batch_n, last_idx);
    convE_kernel<<<12500, 256, 0, stream>>>(emb, Ebf);
    w1_kernel<<<2048, 128, 0, stream>>>(x, W1w, W1b, last_idx, w1_vn);
    halpha_kernel<<<1600, 256, 0, stream>>>(x, W2w, W2b, qw, qb, w1_vn, batch_n, alpha);
    sg_kernel<<<2048, 128, 0, stream>>>(x, alpha, last_idx, s_g);
    sh_kernel<<<2048, 128, 0, stream>>>(x, s_g, W3w, W3b, last_idx, sh_bf);
    final_kernel<<<dim3(16, 782), 256, 0, stream>>>(sh_bf, Ebf, out);
}